// Round 23
// baseline (272.795 us; speedup 1.0000x reference)
//
#include <hip/hip_runtime.h>
#include <hip/hip_bf16.h>
#include <cstdint>
#include <cstddef>

#define HIDDEN 2048
#define NHEADS 16
#define NKV    8
#define HD     128
#define QS     (NHEADS*HD)      // 2048
#define KVS    (NKV*HD)         // 1024
#define OC     (QS + 2*KVS)     // 4096
#define BB     2
#define SS     2048
#define ROWS   (BB*SS)          // 4096

typedef __bf16 bf16;
typedef __bf16 bf16x8 __attribute__((ext_vector_type(8)));
typedef __bf16 bf16x4 __attribute__((ext_vector_type(4)));
typedef float  f32x4  __attribute__((ext_vector_type(4)));
typedef float  f32x2  __attribute__((ext_vector_type(2)));
typedef float  f32x16 __attribute__((ext_vector_type(16)));
typedef int    i32x4  __attribute__((ext_vector_type(4)));

// raw v_exp_f32 (2^x); avoids the precise OCML exp2f path (R18 regression)
__device__ __forceinline__ float fexp2(float x) {
#if __has_builtin(__builtin_amdgcn_exp2f)
  return __builtin_amdgcn_exp2f(x);
#else
  return __expf(x * 0.6931471805599453f);
#endif
}

// Blocked operand layout (K=2048, KT=32): element (row,k) lives at
//   P=row>>7, rr=row&127, kt=k>>6, kk=k&63
//   rg=rr>>5, l31=rr&31, s=kk>>4, hg=(kk>>3)&1, e=kk&7
//   c=((rg*4+s)*32+l31)*2+hg ;  addr = ((P*32+kt)<<13) + c*8 + e   [elements]
// GEMM stages tile (P,kt) with gll16 from base+(c*16B): perfectly coalesced,
// and LDS ends up in MFMA-fragment order (R22-verified reads).

// ---------------- f32 -> blocked bf16 convert (single segment) ----------------
__global__ __launch_bounds__(256) void k_cvtb(const float* __restrict__ src,
                                              bf16* __restrict__ dst, int nchunks) {
  int G = blockIdx.x * blockDim.x + threadIdx.x;
  int stride = gridDim.x * blockDim.x;
  for (; G < nchunks; G += stride) {
    int c = G & 1023, tile = G >> 10;
    int P = tile >> 5, kt = tile & 31;
    int hg = c & 1, l31 = (c >> 1) & 31, s = (c >> 6) & 3, rg = c >> 8;
    int row = P * 128 + rg * 32 + l31;
    int k = kt * 64 + s * 16 + hg * 8;
    const f32x4* sp = (const f32x4*)(src + (size_t)row * 2048 + k);
    f32x4 a = sp[0], b2 = sp[1];
    bf16x8 o;
    o[0]=(bf16)a[0]; o[1]=(bf16)a[1]; o[2]=(bf16)a[2]; o[3]=(bf16)a[3];
    o[4]=(bf16)b2[0]; o[5]=(bf16)b2[1]; o[6]=(bf16)b2[2]; o[7]=(bf16)b2[3];
    *(bf16x8*)(dst + (size_t)G * 8) = o;
  }
}

// ---------------- merged f32 -> blocked bf16: 2 segments (hid + wqkv) ----------------
__global__ __launch_bounds__(256) void k_cvtb2(const float* __restrict__ s0, bf16* __restrict__ d0, int n0,
                                               const float* __restrict__ s1, bf16* __restrict__ d1, int n1) {
  int G = blockIdx.x * blockDim.x + threadIdx.x;
  int stride = gridDim.x * blockDim.x;
  int total = n0 + n1;
  for (; G < total; G += stride) {
    const float* src; bf16* dst; int g;
    if (G < n0) { src = s0; dst = d0; g = G; }
    else        { src = s1; dst = d1; g = G - n0; }
    int c = g & 1023, tile = g >> 10;
    int P = tile >> 5, kt = tile & 31;
    int hg = c & 1, l31 = (c >> 1) & 31, s = (c >> 6) & 3, rg = c >> 8;
    int row = P * 128 + rg * 32 + l31;
    int k = kt * 64 + s * 16 + hg * 8;
    const f32x4* sp = (const f32x4*)(src + (size_t)row * 2048 + k);
    f32x4 a = sp[0], b2 = sp[1];
    bf16x8 o;
    o[0]=(bf16)a[0]; o[1]=(bf16)a[1]; o[2]=(bf16)a[2]; o[3]=(bf16)a[3];
    o[4]=(bf16)b2[0]; o[5]=(bf16)b2[1]; o[6]=(bf16)b2[2]; o[7]=(bf16)b2[3];
    *(bf16x8*)(dst + (size_t)g * 8) = o;
  }
}

// ---------------- RoPE cos/sin table: tbl[pos][i] = {cos, sin} ----------------
__global__ __launch_bounds__(256) void k_table(float* __restrict__ tbl) {
  int t = blockIdx.x * blockDim.x + threadIdx.x;   // t < SS*64
  int pos = t >> 6, i = t & 63;
  float freq = powf(10000.0f, -(float)i / 64.0f);
  float ang = (float)pos * freq;
  float sv, cv;
  sincosf(ang, &sv, &cv);
  f32x2 v; v[0] = cv; v[1] = sv;
  ((f32x2*)tbl)[t] = v;
}

// ---------------- async global->LDS helper ----------------
__device__ __forceinline__ void gll16(const void* g, void* l) {
  __builtin_amdgcn_global_load_lds((const __attribute__((address_space(1))) void*)g,
                                   (__attribute__((address_space(3))) void*)l, 16, 0, 0);
}

// ---------------- GEMM on BLOCKED operands: C[M][N] = A[M][K] * Bw[N][K]^T ----------------
// BK=64, 128x128 tile, 4 waves, 32x32x16 MFMA. gll16 sources are linear within
// each 16KB tile -> perfect coalescing; LDS fragment-order (R22-verified).
template <typename OT>
__global__ __launch_bounds__(256) void k_gemm(const bf16* __restrict__ A,
                                              const bf16* __restrict__ Bw,
                                              OT* __restrict__ C,
                                              int M, int N, int K) {
  const int tid = threadIdx.x;
  const int lane = tid & 63;
  const int w = tid >> 6;
  // XCD-aware block swizzle (nwg % 8 == 0 for both GEMMs: 1024, 512)
  const int H = blockIdx.x + gridDim.x * blockIdx.y;
  const int cpx = (gridDim.x * gridDim.y) >> 3;
  const int swz = (H & 7) * cpx + (H >> 3);
  const int bx = swz % gridDim.x, by = swz / gridDim.x;
  const int m0 = by * 128, n0 = bx * 128;
  __shared__ bf16 As[128 * 64];
  __shared__ bf16 Bs[128 * 64];
  f32x16 acc[2][2] = {};
  const int wm = (w >> 1) * 64, wn = (w & 1) * 64;
  const int l31 = lane & 31, hg = lane >> 5;
  const int rgA = (w >> 1) * 2;      // wave's first A row-group (of 32 rows)
  const int rgB = (w & 1) * 2;       // wave's first B row-group
  const int KT = K >> 6;
  for (int kt = 0; kt < KT; ++kt) {
    __syncthreads();
    const size_t tA = ((size_t)((m0 >> 7) * KT + kt)) << 13;  // element base of A tile
    const size_t tB = ((size_t)((n0 >> 7) * KT + kt)) << 13;
    #pragma unroll
    for (int i = 0; i < 4; ++i) {
      int c = tid + i * 256;          // 1024 chunks of 16B per matrix
      gll16(A + tA + (size_t)c * 8, As + (size_t)(c & ~63) * 8);
      gll16(Bw + tB + (size_t)c * 8, Bs + (size_t)(c & ~63) * 8);
    }
    asm volatile("s_waitcnt vmcnt(0)" ::: "memory");
    __syncthreads();
    bf16x8 af[2][4], bfv[2][4];
    #pragma unroll
    for (int i = 0; i < 2; ++i)
      #pragma unroll
      for (int s = 0; s < 4; ++s)
        af[i][s] = *(const bf16x8*)((char*)As + (((rgA + i) * 4 + s) * 1024 + l31 * 32 + hg * 16));
    #pragma unroll
    for (int j = 0; j < 2; ++j)
      #pragma unroll
      for (int s = 0; s < 4; ++s)
        bfv[j][s] = *(const bf16x8*)((char*)Bs + (((rgB + j) * 4 + s) * 1024 + l31 * 32 + hg * 16));
    #pragma unroll
    for (int i = 0; i < 2; ++i)
      #pragma unroll
      for (int j = 0; j < 2; ++j)
        #pragma unroll
        for (int s = 0; s < 4; ++s)
          acc[i][j] = __builtin_amdgcn_mfma_f32_32x32x16_bf16(af[i][s], bfv[j][s], acc[i][j], 0, 0, 0);
  }
  #pragma unroll
  for (int i = 0; i < 2; ++i)
    #pragma unroll
    for (int j = 0; j < 2; ++j) {
      int col = n0 + wn + j * 32 + l31;
      #pragma unroll
      for (int reg = 0; reg < 16; ++reg) {
        int row = m0 + wm + i * 32 + 4 * hg + (reg & 3) + 8 * (reg >> 2);
        C[(size_t)row * N + col] = (OT)acc[i][j][reg];
      }
    }
}

// ---------------- per-head RMSNorm + RoPE; one wave per (b,s,head24) ----------------
// Q heads pre-scaled by scl2 = 128^-0.5 * log2(e) (log2-domain softmax).
__global__ __launch_bounds__(256) void k_ropenorm(const bf16* __restrict__ qkv,
                                                  bf16* __restrict__ qb, bf16* __restrict__ kb,
                                                  const float* __restrict__ tbl,
                                                  const int* __restrict__ pos,
                                                  const float* __restrict__ qw,
                                                  const float* __restrict__ kw) {
  int gw = blockIdx.x * 4 + (threadIdx.x >> 6);
  int lane = threadIdx.x & 63;
  int h = gw % 24;
  int rem = gw / 24;
  int s = rem & (SS - 1);
  int b = rem >> 11;
  size_t row = (size_t)b * SS + s;
  int col0 = (h < 16) ? h * HD : QS + (h - 16) * HD;
  unsigned u = *(const unsigned*)(qkv + row * OC + col0 + lane * 2);
  float x0 = __uint_as_float((u & 0xffffu) << 16);
  float x1 = __uint_as_float(u & 0xffff0000u);
  float ssq = x0 * x0 + x1 * x1;
  for (int m = 1; m < 64; m <<= 1) ssq += __shfl_xor(ssq, m, 64);
  float r = rsqrtf(ssq * (1.0f / 128.0f) + 1e-6f);
  const float* wv = (h < 16) ? qw : kw;
  float y0 = x0 * r * wv[lane * 2], y1 = x1 * r * wv[lane * 2 + 1];
  float p0 = __shfl_xor(y0, 32, 64), p1 = __shfl_xor(y1, 32, 64);
  int p = pos[row];
  f32x4 cs = *(const f32x4*)(tbl + (size_t)p * 128 + (lane & 31) * 4); // c0,s0,c1,s1
  float o0, o1;
  if (lane < 32) { o0 = y0 * cs[0] - p0 * cs[1]; o1 = y1 * cs[2] - p1 * cs[3]; }
  else           { o0 = y0 * cs[0] + p0 * cs[1]; o1 = y1 * cs[2] + p1 * cs[3]; }
  bf16* dst; size_t drow;
  if (h < 16) {
    const float scl2 = 0.12753102f;   // (1/sqrt(128)) * log2(e), folded into Q
    o0 *= scl2; o1 *= scl2;
    dst = qb; drow = ((size_t)b * NHEADS + h) * SS + s;
  } else {
    dst = kb; drow = ((size_t)b * NKV + (h - 16)) * SS + s;
  }
  bf16 v0 = (bf16)o0, v1 = (bf16)o1;
  unsigned short q0, q1;
  __builtin_memcpy(&q0, &v0, 2); __builtin_memcpy(&q1, &v1, 2);
  *(unsigned*)(dst + drow * HD + lane * 2) = (unsigned)q0 | ((unsigned)q1 << 16);
}

// ---------------- V transpose: qkv v-cols -> vT[b][kv][d][s] ----------------
__global__ __launch_bounds__(256) void k_vt(const bf16* __restrict__ qkv,
                                            bf16* __restrict__ vT) {
  __shared__ bf16 T[64 * 136];       // 64 s-rows x (128 + 8 pad)
  int tid = threadIdx.x;
  int st = blockIdx.x, kv = blockIdx.y, b = blockIdx.z;
  int s0 = st * 64;
  for (int i = 0; i < 4; ++i) {      // 1024 chunks = 64 rows x 16 d-chunks
    int c = tid + i * 256;
    int sl = c >> 4, dc = c & 15;
    i32x4 v = *(const i32x4*)(qkv + (size_t)(b * SS + s0 + sl) * OC + QS + KVS + kv * HD + dc * 8);
    *(i32x4*)(T + sl * 136 + dc * 8) = v;
  }
  __syncthreads();
  for (int i = 0; i < 4; ++i) {
    int c = tid + i * 256;
    int d = c >> 3, sg = c & 7;
    bf16x8 o;
    for (int j = 0; j < 8; ++j) o[j] = T[(sg * 8 + j) * 136 + d];
    *(bf16x8*)(vT + ((size_t)(b * NKV + kv) * HD + d) * SS + s0 + sg * 8) = o;
  }
}

// ---------------- flash attention: XCD-locality + load-balanced mapping; blocked attn_o write ----------------
__global__ __launch_bounds__(256) void k_attn9(const bf16* __restrict__ qb,
                                               const bf16* __restrict__ kb,
                                               const bf16* __restrict__ vT,
                                               bf16* __restrict__ out) {
  __shared__ bf16 Kl[64 * 128];      // [kv][d], rows XOR-swizzled by (row&7)<<4
  __shared__ bf16 Vl[128 * 64];      // [d][kv], rows XOR-swizzled by (row&7)<<4
  __shared__ bf16 Pl[4][16 * 64];    // per-wave P[q][kv], row-XOR swizzled (128B rows)
  const int tid = threadIdx.x, lane = tid & 63, w = tid >> 6;
  const int L = blockIdx.x + 32 * (blockIdx.y + 16 * blockIdx.z);
  const int r8 = L & 7;
  const int c4 = (L >> 3) & 3;
  const int i32_ = L >> 5;           // 0..31
  const int g = r8 * 4 + c4;         // 0..31
  const int h = g >> 1, b = g & 1;
  const int a_ = i32_ & 7, m_ = i32_ >> 3;
  const int qt = (m_ == 0) ? a_ : (m_ == 1) ? (15 - a_) : (m_ == 2) ? (16 + a_) : (31 - a_);
  const int kvh = h >> 1;            // == r8 for every block on XCD r8
  const int lr = lane & 15, lg = lane >> 4;
  const int qbase = qt * 64 + w * 16;
  const float NEG = -3.0e38f;
  bf16x8 qf[4];
  {
    const bf16* qrow = qb + ((size_t)(b * NHEADS + h) * SS + qbase + lr) * HD;
    #pragma unroll
    for (int ks = 0; ks < 4; ++ks) qf[ks] = *(const bf16x8*)(qrow + ks * 32 + lg * 8);
  }
  f32x4 acc[8] = {};                 // acc[nt][r] = O[q=lg*4+r][d=nt*16+lr]
  float m_r = NEG, l_r = 0.0f;       // m_r in log2 units
  const bf16* Kg = kb + (size_t)(b * NKV + kvh) * SS * HD;
  const bf16* Vg = vT + (size_t)(b * NKV + kvh) * HD * SS;
  for (int t = 0; t <= qt; ++t) {
    const int kv0 = t * 64;
    __syncthreads();                 // protect previous tile's LDS from overwrite
    #pragma unroll
    for (int i = 0; i < 4; ++i) {
      int c = tid + i * 256;
      int r_ = c >> 4;
      int ch = (c & 15) ^ (r_ & 7);
      gll16(Kg + (size_t)(kv0 + r_) * HD + ch * 8, Kl + (size_t)(c & ~63) * 8);
    }
    #pragma unroll
    for (int i = 0; i < 4; ++i) {
      int c = tid + i * 256;
      int d = c >> 3;
      int ch = (c & 7) ^ (d & 7);
      gll16(Vg + (size_t)d * SS + kv0 + ch * 8, Vl + (size_t)(c & ~63) * 8);
    }
    asm volatile("s_waitcnt vmcnt(0)" ::: "memory");
    __syncthreads();
    // ---- QK^T: S^T[kv][q] via MFMA (scores already in log2 domain) ----
    f32x4 sf[4];
    __builtin_amdgcn_s_setprio(1);
    #pragma unroll
    for (int mt = 0; mt < 4; ++mt) {
      f32x4 a2 = {0.f, 0.f, 0.f, 0.f};
      const int rrow = mt * 16 + lr;
      #pragma unroll
      for (int ks = 0; ks < 4; ++ks) {
        bf16x8 kf = *(const bf16x8*)((char*)Kl + ((rrow * 256 + ks * 64 + lg * 16) ^ ((rrow & 7) << 4)));
        a2 = __builtin_amdgcn_mfma_f32_16x16x32_bf16(kf, qf[ks], a2, 0, 0, 0);
      }
      sf[mt] = a2;
    }
    __builtin_amdgcn_s_setprio(0);
    // ---- causal mask (diagonal tile only) + row-max ----
    const int qg = qbase + lr;
    float pm = NEG;
    if (t == qt) {
      #pragma unroll
      for (int mt = 0; mt < 4; ++mt)
        #pragma unroll
        for (int r = 0; r < 4; ++r) {
          int kvg = kv0 + mt * 16 + lg * 4 + r;
          float v = sf[mt][r];
          if (kvg > qg) v = NEG;
          sf[mt][r] = v;
          pm = fmaxf(pm, v);
        }
    } else {
      #pragma unroll
      for (int mt = 0; mt < 4; ++mt)
        #pragma unroll
        for (int r = 0; r < 4; ++r) pm = fmaxf(pm, sf[mt][r]);
    }
    pm = fmaxf(pm, __shfl_xor(pm, 16, 64));
    pm = fmaxf(pm, __shfl_xor(pm, 32, 64));
    // ---- T13 defer-max (8 nats = 11.54 log2 units) ----
    if (!__all(pm <= m_r + 11.5415603f)) {
      const float mn = fmaxf(m_r, pm);
      const float scale = fexp2(m_r - mn);
      float sr[4];
      #pragma unroll
      for (int r = 0; r < 4; ++r) sr[r] = __shfl(scale, lg * 4 + r, 64);
      #pragma unroll
      for (int nt = 0; nt < 8; ++nt)
        #pragma unroll
        for (int r = 0; r < 4; ++r) acc[nt][r] *= sr[r];
      l_r *= scale;
      m_r = mn;
    }
    // ---- P = 2^(S - m_r); row-sum into l_r ----
    float ts = 0.f;
    #pragma unroll
    for (int mt = 0; mt < 4; ++mt)
      #pragma unroll
      for (int r = 0; r < 4; ++r) {
        float pv = fexp2(sf[mt][r] - m_r);
        sf[mt][r] = pv;
        ts += pv;
      }
    ts += __shfl_xor(ts, 16, 64);
    ts += __shfl_xor(ts, 32, 64);
    l_r += ts;
    // ---- P -> per-wave swizzled LDS ----
    #pragma unroll
    for (int mt = 0; mt < 4; ++mt) {
      bf16x4 pk;
      #pragma unroll
      for (int r = 0; r < 4; ++r) pk[r] = (bf16)sf[mt][r];
      *(bf16x4*)((char*)&Pl[w][0] + ((lr * 128 + mt * 32 + lg * 8) ^ ((lr & 7) << 4))) = pk;
    }
    // ---- PV ----
    __builtin_amdgcn_s_setprio(1);
    #pragma unroll
    for (int kk = 0; kk < 2; ++kk) {
      bf16x8 pa = *(const bf16x8*)((char*)&Pl[w][0] + ((lr * 128 + kk * 64 + lg * 16) ^ ((lr & 7) << 4)));
      #pragma unroll
      for (int nt = 0; nt < 8; ++nt) {
        const int d = nt * 16 + lr;
        bf16x8 vbf = *(const bf16x8*)((char*)Vl + ((d * 128 + kk * 64 + lg * 16) ^ ((d & 7) << 4)));
        acc[nt] = __builtin_amdgcn_mfma_f32_16x16x32_bf16(pa, vbf, acc[nt], 0, 0, 0);
      }
    }
    __builtin_amdgcn_s_setprio(0);
  }
  // ---- epilogue: normalize and store attn_o in BLOCKED layout (feeds GEMM2's A) ----
  const float inv = 1.0f / l_r;
  float ir[4];
  #pragma unroll
  for (int r = 0; r < 4; ++r) ir[r] = __shfl(inv, lg * 4 + r, 64);
  const int hgE = (lr >> 3) & 1, eE = lr & 7;
  #pragma unroll
  for (int nt = 0; nt < 8; ++nt) {
    const int ktE = h * 2 + (nt >> 2);   // col tile (K=QS=2048, KT=32)
    const int sE = nt & 3;
    #pragma unroll
    for (int r = 0; r < 4; ++r) {
      int rowi = b * SS + qbase + lg * 4 + r;
      int P = rowi >> 7, rr = rowi & 127;
      int rg = rr >> 5, l31r = rr & 31;
      int cE = ((rg * 4 + sE) * 32 + l31r) * 2 + hgE;
      size_t addr = (((size_t)(P * 32 + ktE)) << 13) + (size_t)cE * 8 + eE;
      out[addr] = (bf16)(acc[nt][r] * ir[r]);
    }
  }
}

// ---------------- launcher ----------------
// NOTE: wo_bf aliases k_buf (region C) -> the wo convert MUST run after attention.
extern "C" void kernel_launch(void* const* d_in, const int* in_sizes, int n_in,
                              void* d_out, int out_size, void* d_ws, size_t ws_size,
                              hipStream_t stream) {
  const int*   pos  = (const int*)d_in[0];
  const float* hid  = (const float*)d_in[1];
  const float* wqkv = (const float*)d_in[2];
  const float* wo   = (const float*)d_in[3];
  const float* qw   = (const float*)d_in[4];
  const float* kw   = (const float*)d_in[5];
  char* ws = (char*)d_ws;
  bf16* hid_bf  = (bf16*)(ws + 0);          // 16MB blocked, reused as attn_out (blocked)
  bf16* attn_o  = hid_bf;
  bf16* wqkv_bf = (bf16*)(ws + 16777216);   // 16MB blocked, reused as q_buf
  bf16* q_buf   = wqkv_bf;
  bf16* k_buf   = (bf16*)(ws + 33554432);   // 8MB, reused as wo_bf (blocked) AFTER attn
  bf16* wo_bf   = k_buf;
  bf16* qkv     = (bf16*)(ws + 41943040);   // 32MB (row-major)
  bf16* vT      = (bf16*)(ws + 75497472);   // 8MB
  float* tbl    = (float*)(ws + 83886080);  // 1MB

  k_cvtb2<<<dim3(2048), dim3(256), 0, stream>>>(
      hid, hid_bf, ROWS * HIDDEN / 8,
      wqkv, wqkv_bf, OC * HIDDEN / 8);
  k_table<<<dim3(512), dim3(256), 0, stream>>>(tbl);
  k_gemm<bf16><<<dim3(OC / 128, ROWS / 128), dim3(256), 0, stream>>>(
      hid_bf, wqkv_bf, qkv, ROWS, OC, HIDDEN);
  k_ropenorm<<<dim3(ROWS * 24 / 4), dim3(256), 0, stream>>>(
      qkv, q_buf, k_buf, tbl, pos, qw, kw);
  k_vt<<<dim3(SS / 64, NKV, BB), dim3(256), 0, stream>>>(qkv, vT);
  k_attn9<<<dim3(SS / 64, NHEADS, BB), dim3(256), 0, stream>>>(
      q_buf, k_buf, vT, attn_o);
  k_cvtb<<<dim3(2048), dim3(256), 0, stream>>>(wo, wo_bf, HIDDEN * QS / 8);
  k_gemm<float><<<dim3(HIDDEN / 128, ROWS / 128), dim3(256), 0, stream>>>(
      attn_o, wo_bf, (float*)d_out, ROWS, HIDDEN, QS);
}

// Round 24
// 266.120 us; speedup vs baseline: 1.0251x; 1.0251x over previous
//
#include <hip/hip_runtime.h>
#include <hip/hip_bf16.h>
#include <cstdint>
#include <cstddef>

#define HIDDEN 2048
#define NHEADS 16
#define NKV    8
#define HD     128
#define QS     (NHEADS*HD)      // 2048
#define KVS    (NKV*HD)         // 1024
#define OC     (QS + 2*KVS)     // 4096
#define BB     2
#define SS     2048
#define ROWS   (BB*SS)          // 4096

typedef __bf16 bf16;
typedef __bf16 bf16x8 __attribute__((ext_vector_type(8)));
typedef __bf16 bf16x4 __attribute__((ext_vector_type(4)));
typedef float  f32x4  __attribute__((ext_vector_type(4)));
typedef float  f32x2  __attribute__((ext_vector_type(2)));
typedef float  f32x16 __attribute__((ext_vector_type(16)));
typedef int    i32x4  __attribute__((ext_vector_type(4)));

// raw v_exp_f32 (2^x); avoids the precise OCML exp2f path (R18 regression)
__device__ __forceinline__ float fexp2(float x) {
#if __has_builtin(__builtin_amdgcn_exp2f)
  return __builtin_amdgcn_exp2f(x);
#else
  return __expf(x * 0.6931471805599453f);
#endif
}

// Blocked operand layout (K=2048, KT=32): element (row,k) lives at
//   P=row>>7, rr=row&127, kt=k>>6, kk=k&63
//   rg=rr>>5, l31=rr&31, s=kk>>4, hg=(kk>>3)&1, e=kk&7
//   c=((rg*4+s)*32+l31)*2+hg ;  addr = ((P*32+kt)<<13) + c*8 + e   [elements]

// ---------------- f32 -> blocked bf16 convert (single segment) ----------------
__global__ __launch_bounds__(256) void k_cvtb(const float* __restrict__ src,
                                              bf16* __restrict__ dst, int nchunks) {
  int G = blockIdx.x * blockDim.x + threadIdx.x;
  int stride = gridDim.x * blockDim.x;
  for (; G < nchunks; G += stride) {
    int c = G & 1023, tile = G >> 10;
    int P = tile >> 5, kt = tile & 31;
    int hg = c & 1, l31 = (c >> 1) & 31, s = (c >> 6) & 3, rg = c >> 8;
    int row = P * 128 + rg * 32 + l31;
    int k = kt * 64 + s * 16 + hg * 8;
    const f32x4* sp = (const f32x4*)(src + (size_t)row * 2048 + k);
    f32x4 a = sp[0], b2 = sp[1];
    bf16x8 o;
    o[0]=(bf16)a[0]; o[1]=(bf16)a[1]; o[2]=(bf16)a[2]; o[3]=(bf16)a[3];
    o[4]=(bf16)b2[0]; o[5]=(bf16)b2[1]; o[6]=(bf16)b2[2]; o[7]=(bf16)b2[3];
    *(bf16x8*)(dst + (size_t)G * 8) = o;
  }
}

// ---------------- merged f32 -> blocked bf16: 2 segments (hid + wqkv) ----------------
__global__ __launch_bounds__(256) void k_cvtb2(const float* __restrict__ s0, bf16* __restrict__ d0, int n0,
                                               const float* __restrict__ s1, bf16* __restrict__ d1, int n1) {
  int G = blockIdx.x * blockDim.x + threadIdx.x;
  int stride = gridDim.x * blockDim.x;
  int total = n0 + n1;
  for (; G < total; G += stride) {
    const float* src; bf16* dst; int g;
    if (G < n0) { src = s0; dst = d0; g = G; }
    else        { src = s1; dst = d1; g = G - n0; }
    int c = g & 1023, tile = g >> 10;
    int P = tile >> 5, kt = tile & 31;
    int hg = c & 1, l31 = (c >> 1) & 31, s = (c >> 6) & 3, rg = c >> 8;
    int row = P * 128 + rg * 32 + l31;
    int k = kt * 64 + s * 16 + hg * 8;
    const f32x4* sp = (const f32x4*)(src + (size_t)row * 2048 + k);
    f32x4 a = sp[0], b2 = sp[1];
    bf16x8 o;
    o[0]=(bf16)a[0]; o[1]=(bf16)a[1]; o[2]=(bf16)a[2]; o[3]=(bf16)a[3];
    o[4]=(bf16)b2[0]; o[5]=(bf16)b2[1]; o[6]=(bf16)b2[2]; o[7]=(bf16)b2[3];
    *(bf16x8*)(dst + (size_t)g * 8) = o;
  }
}

// ---------------- RoPE cos/sin table: tbl[pos][i] = {cos, sin} ----------------
__global__ __launch_bounds__(256) void k_table(float* __restrict__ tbl) {
  int t = blockIdx.x * blockDim.x + threadIdx.x;   // t < SS*64
  int pos = t >> 6, i = t & 63;
  float freq = powf(10000.0f, -(float)i / 64.0f);
  float ang = (float)pos * freq;
  float sv, cv;
  sincosf(ang, &sv, &cv);
  f32x2 v; v[0] = cv; v[1] = sv;
  ((f32x2*)tbl)[t] = v;
}

// ---------------- async global->LDS helper ----------------
__device__ __forceinline__ void gll16(const void* g, void* l) {
  __builtin_amdgcn_global_load_lds((const __attribute__((address_space(1))) void*)g,
                                   (__attribute__((address_space(3))) void*)l, 16, 0, 0);
}

// ---------------- GEMM on BLOCKED operands: C[M][N] = A[M][K] * Bw[N][K]^T ----------------
// BK=64, 128x128 tile, 4 waves, 32x32x16 MFMA, fragment-order LDS.
// K-loop START IS STAGGERED per co-resident block (phase = (lin>>8)&3): the 4
// blocks sharing a CU hit their vmcnt(0)+barrier drains at different times, so
// the CU's MFMA pipe stays fed (anti-lockstep). Sum over K is order-invariant.
template <typename OT>
__global__ __launch_bounds__(256) void k_gemm(const bf16* __restrict__ A,
                                              const bf16* __restrict__ Bw,
                                              OT* __restrict__ C,
                                              int M, int N, int K) {
  const int tid = threadIdx.x;
  const int lane = tid & 63;
  const int w = tid >> 6;
  const int lin = blockIdx.x + gridDim.x * blockIdx.y;
  // XCD-aware block swizzle (nwg % 8 == 0 for both GEMMs: 1024, 512)
  const int cpx = (gridDim.x * gridDim.y) >> 3;
  const int swz = (lin & 7) * cpx + (lin >> 3);
  const int bx = swz % gridDim.x, by = swz / gridDim.x;
  const int m0 = by * 128, n0 = bx * 128;
  __shared__ bf16 As[128 * 64];
  __shared__ bf16 Bs[128 * 64];
  f32x16 acc[2][2] = {};
  const int wm = (w >> 1) * 64, wn = (w & 1) * 64;
  const int l31 = lane & 31, hg = lane >> 5;
  const int rgA = (w >> 1) * 2;      // wave's first A row-group (of 32 rows)
  const int rgB = (w & 1) * 2;       // wave's first B row-group
  const int KT = K >> 6;
  const int kt0 = ((lin >> 8) & 3) * (KT >> 2);   // anti-lockstep phase
  for (int it = 0; it < KT; ++it) {
    int kt = kt0 + it; if (kt >= KT) kt -= KT;
    __syncthreads();
    const size_t tA = ((size_t)((m0 >> 7) * KT + kt)) << 13;  // element base of A tile
    const size_t tB = ((size_t)((n0 >> 7) * KT + kt)) << 13;
    #pragma unroll
    for (int i = 0; i < 4; ++i) {
      int c = tid + i * 256;          // 1024 chunks of 16B per matrix
      gll16(A + tA + (size_t)c * 8, As + (size_t)(c & ~63) * 8);
      gll16(Bw + tB + (size_t)c * 8, Bs + (size_t)(c & ~63) * 8);
    }
    asm volatile("s_waitcnt vmcnt(0)" ::: "memory");
    __syncthreads();
    bf16x8 af[2][4], bfv[2][4];
    #pragma unroll
    for (int i = 0; i < 2; ++i)
      #pragma unroll
      for (int s = 0; s < 4; ++s)
        af[i][s] = *(const bf16x8*)((char*)As + (((rgA + i) * 4 + s) * 1024 + l31 * 32 + hg * 16));
    #pragma unroll
    for (int j = 0; j < 2; ++j)
      #pragma unroll
      for (int s = 0; s < 4; ++s)
        bfv[j][s] = *(const bf16x8*)((char*)Bs + (((rgB + j) * 4 + s) * 1024 + l31 * 32 + hg * 16));
    #pragma unroll
    for (int i = 0; i < 2; ++i)
      #pragma unroll
      for (int j = 0; j < 2; ++j)
        #pragma unroll
        for (int s = 0; s < 4; ++s)
          acc[i][j] = __builtin_amdgcn_mfma_f32_32x32x16_bf16(af[i][s], bfv[j][s], acc[i][j], 0, 0, 0);
  }
  #pragma unroll
  for (int i = 0; i < 2; ++i)
    #pragma unroll
    for (int j = 0; j < 2; ++j) {
      int col = n0 + wn + j * 32 + l31;
      #pragma unroll
      for (int reg = 0; reg < 16; ++reg) {
        int row = m0 + wm + i * 32 + 4 * hg + (reg & 3) + 8 * (reg >> 2);
        C[(size_t)row * N + col] = (OT)acc[i][j][reg];
      }
    }
}

// ---------------- per-head RMSNorm + RoPE; one wave per (b,s,head24) ----------------
// Q heads pre-scaled by scl2 = 128^-0.5 * log2(e) (log2-domain softmax).
__global__ __launch_bounds__(256) void k_ropenorm(const bf16* __restrict__ qkv,
                                                  bf16* __restrict__ qb, bf16* __restrict__ kb,
                                                  const float* __restrict__ tbl,
                                                  const int* __restrict__ pos,
                                                  const float* __restrict__ qw,
                                                  const float* __restrict__ kw) {
  int gw = blockIdx.x * 4 + (threadIdx.x >> 6);
  int lane = threadIdx.x & 63;
  int h = gw % 24;
  int rem = gw / 24;
  int s = rem & (SS - 1);
  int b = rem >> 11;
  size_t row = (size_t)b * SS + s;
  int col0 = (h < 16) ? h * HD : QS + (h - 16) * HD;
  unsigned u = *(const unsigned*)(qkv + row * OC + col0 + lane * 2);
  float x0 = __uint_as_float((u & 0xffffu) << 16);
  float x1 = __uint_as_float(u & 0xffff0000u);
  float ssq = x0 * x0 + x1 * x1;
  for (int m = 1; m < 64; m <<= 1) ssq += __shfl_xor(ssq, m, 64);
  float r = rsqrtf(ssq * (1.0f / 128.0f) + 1e-6f);
  const float* wv = (h < 16) ? qw : kw;
  float y0 = x0 * r * wv[lane * 2], y1 = x1 * r * wv[lane * 2 + 1];
  float p0 = __shfl_xor(y0, 32, 64), p1 = __shfl_xor(y1, 32, 64);
  int p = pos[row];
  f32x4 cs = *(const f32x4*)(tbl + (size_t)p * 128 + (lane & 31) * 4); // c0,s0,c1,s1
  float o0, o1;
  if (lane < 32) { o0 = y0 * cs[0] - p0 * cs[1]; o1 = y1 * cs[2] - p1 * cs[3]; }
  else           { o0 = y0 * cs[0] + p0 * cs[1]; o1 = y1 * cs[2] + p1 * cs[3]; }
  bf16* dst; size_t drow;
  if (h < 16) {
    const float scl2 = 0.12753102f;   // (1/sqrt(128)) * log2(e), folded into Q
    o0 *= scl2; o1 *= scl2;
    dst = qb; drow = ((size_t)b * NHEADS + h) * SS + s;
  } else {
    dst = kb; drow = ((size_t)b * NKV + (h - 16)) * SS + s;
  }
  bf16 v0 = (bf16)o0, v1 = (bf16)o1;
  unsigned short q0, q1;
  __builtin_memcpy(&q0, &v0, 2); __builtin_memcpy(&q1, &v1, 2);
  *(unsigned*)(dst + drow * HD + lane * 2) = (unsigned)q0 | ((unsigned)q1 << 16);
}

// ---------------- V transpose: qkv v-cols -> vT[b][kv][d][s] ----------------
__global__ __launch_bounds__(256) void k_vt(const bf16* __restrict__ qkv,
                                            bf16* __restrict__ vT) {
  __shared__ bf16 T[64 * 136];       // 64 s-rows x (128 + 8 pad)
  int tid = threadIdx.x;
  int st = blockIdx.x, kv = blockIdx.y, b = blockIdx.z;
  int s0 = st * 64;
  for (int i = 0; i < 4; ++i) {      // 1024 chunks = 64 rows x 16 d-chunks
    int c = tid + i * 256;
    int sl = c >> 4, dc = c & 15;
    i32x4 v = *(const i32x4*)(qkv + (size_t)(b * SS + s0 + sl) * OC + QS + KVS + kv * HD + dc * 8);
    *(i32x4*)(T + sl * 136 + dc * 8) = v;
  }
  __syncthreads();
  for (int i = 0; i < 4; ++i) {
    int c = tid + i * 256;
    int d = c >> 3, sg = c & 7;
    bf16x8 o;
    for (int j = 0; j < 8; ++j) o[j] = T[(sg * 8 + j) * 136 + d];
    *(bf16x8*)(vT + ((size_t)(b * NKV + kv) * HD + d) * SS + s0 + sg * 8) = o;
  }
}

// ---------------- flash attention: XCD-locality + load-balanced mapping; blocked attn_o write ----------------
__global__ __launch_bounds__(256) void k_attn9(const bf16* __restrict__ qb,
                                               const bf16* __restrict__ kb,
                                               const bf16* __restrict__ vT,
                                               bf16* __restrict__ out) {
  __shared__ bf16 Kl[64 * 128];      // [kv][d], rows XOR-swizzled by (row&7)<<4
  __shared__ bf16 Vl[128 * 64];      // [d][kv], rows XOR-swizzled by (row&7)<<4
  __shared__ bf16 Pl[4][16 * 64];    // per-wave P[q][kv], row-XOR swizzled (128B rows)
  const int tid = threadIdx.x, lane = tid & 63, w = tid >> 6;
  const int L = blockIdx.x + 32 * (blockIdx.y + 16 * blockIdx.z);
  const int r8 = L & 7;
  const int c4 = (L >> 3) & 3;
  const int i32_ = L >> 5;           // 0..31
  const int g = r8 * 4 + c4;         // 0..31
  const int h = g >> 1, b = g & 1;
  const int a_ = i32_ & 7, m_ = i32_ >> 3;
  const int qt = (m_ == 0) ? a_ : (m_ == 1) ? (15 - a_) : (m_ == 2) ? (16 + a_) : (31 - a_);
  const int kvh = h >> 1;            // == r8 for every block on XCD r8
  const int lr = lane & 15, lg = lane >> 4;
  const int qbase = qt * 64 + w * 16;
  const float NEG = -3.0e38f;
  bf16x8 qf[4];
  {
    const bf16* qrow = qb + ((size_t)(b * NHEADS + h) * SS + qbase + lr) * HD;
    #pragma unroll
    for (int ks = 0; ks < 4; ++ks) qf[ks] = *(const bf16x8*)(qrow + ks * 32 + lg * 8);
  }
  f32x4 acc[8] = {};                 // acc[nt][r] = O[q=lg*4+r][d=nt*16+lr]
  float m_r = NEG, l_r = 0.0f;       // m_r in log2 units
  const bf16* Kg = kb + (size_t)(b * NKV + kvh) * SS * HD;
  const bf16* Vg = vT + (size_t)(b * NKV + kvh) * HD * SS;
  for (int t = 0; t <= qt; ++t) {
    const int kv0 = t * 64;
    __syncthreads();                 // protect previous tile's LDS from overwrite
    #pragma unroll
    for (int i = 0; i < 4; ++i) {
      int c = tid + i * 256;
      int r_ = c >> 4;
      int ch = (c & 15) ^ (r_ & 7);
      gll16(Kg + (size_t)(kv0 + r_) * HD + ch * 8, Kl + (size_t)(c & ~63) * 8);
    }
    #pragma unroll
    for (int i = 0; i < 4; ++i) {
      int c = tid + i * 256;
      int d = c >> 3;
      int ch = (c & 7) ^ (d & 7);
      gll16(Vg + (size_t)d * SS + kv0 + ch * 8, Vl + (size_t)(c & ~63) * 8);
    }
    asm volatile("s_waitcnt vmcnt(0)" ::: "memory");
    __syncthreads();
    // ---- QK^T: S^T[kv][q] via MFMA (scores already in log2 domain) ----
    f32x4 sf[4];
    __builtin_amdgcn_s_setprio(1);
    #pragma unroll
    for (int mt = 0; mt < 4; ++mt) {
      f32x4 a2 = {0.f, 0.f, 0.f, 0.f};
      const int rrow = mt * 16 + lr;
      #pragma unroll
      for (int ks = 0; ks < 4; ++ks) {
        bf16x8 kf = *(const bf16x8*)((char*)Kl + ((rrow * 256 + ks * 64 + lg * 16) ^ ((rrow & 7) << 4)));
        a2 = __builtin_amdgcn_mfma_f32_16x16x32_bf16(kf, qf[ks], a2, 0, 0, 0);
      }
      sf[mt] = a2;
    }
    __builtin_amdgcn_s_setprio(0);
    // ---- causal mask (diagonal tile only) + row-max ----
    const int qg = qbase + lr;
    float pm = NEG;
    if (t == qt) {
      #pragma unroll
      for (int mt = 0; mt < 4; ++mt)
        #pragma unroll
        for (int r = 0; r < 4; ++r) {
          int kvg = kv0 + mt * 16 + lg * 4 + r;
          float v = sf[mt][r];
          if (kvg > qg) v = NEG;
          sf[mt][r] = v;
          pm = fmaxf(pm, v);
        }
    } else {
      #pragma unroll
      for (int mt = 0; mt < 4; ++mt)
        #pragma unroll
        for (int r = 0; r < 4; ++r) pm = fmaxf(pm, sf[mt][r]);
    }
    pm = fmaxf(pm, __shfl_xor(pm, 16, 64));
    pm = fmaxf(pm, __shfl_xor(pm, 32, 64));
    // ---- T13 defer-max (8 nats = 11.54 log2 units) ----
    if (!__all(pm <= m_r + 11.5415603f)) {
      const float mn = fmaxf(m_r, pm);
      const float scale = fexp2(m_r - mn);
      float sr[4];
      #pragma unroll
      for (int r = 0; r < 4; ++r) sr[r] = __shfl(scale, lg * 4 + r, 64);
      #pragma unroll
      for (int nt = 0; nt < 8; ++nt)
        #pragma unroll
        for (int r = 0; r < 4; ++r) acc[nt][r] *= sr[r];
      l_r *= scale;
      m_r = mn;
    }
    // ---- P = 2^(S - m_r); row-sum into l_r ----
    float ts = 0.f;
    #pragma unroll
    for (int mt = 0; mt < 4; ++mt)
      #pragma unroll
      for (int r = 0; r < 4; ++r) {
        float pv = fexp2(sf[mt][r] - m_r);
        sf[mt][r] = pv;
        ts += pv;
      }
    ts += __shfl_xor(ts, 16, 64);
    ts += __shfl_xor(ts, 32, 64);
    l_r += ts;
    // ---- P -> per-wave swizzled LDS ----
    #pragma unroll
    for (int mt = 0; mt < 4; ++mt) {
      bf16x4 pk;
      #pragma unroll
      for (int r = 0; r < 4; ++r) pk[r] = (bf16)sf[mt][r];
      *(bf16x4*)((char*)&Pl[w][0] + ((lr * 128 + mt * 32 + lg * 8) ^ ((lr & 7) << 4))) = pk;
    }
    // ---- PV ----
    __builtin_amdgcn_s_setprio(1);
    #pragma unroll
    for (int kk = 0; kk < 2; ++kk) {
      bf16x8 pa = *(const bf16x8*)((char*)&Pl[w][0] + ((lr * 128 + kk * 64 + lg * 16) ^ ((lr & 7) << 4)));
      #pragma unroll
      for (int nt = 0; nt < 8; ++nt) {
        const int d = nt * 16 + lr;
        bf16x8 vbf = *(const bf16x8*)((char*)Vl + ((d * 128 + kk * 64 + lg * 16) ^ ((d & 7) << 4)));
        acc[nt] = __builtin_amdgcn_mfma_f32_16x16x32_bf16(pa, vbf, acc[nt], 0, 0, 0);
      }
    }
    __builtin_amdgcn_s_setprio(0);
  }
  // ---- epilogue: normalize and store attn_o in BLOCKED layout (feeds GEMM2's A) ----
  const float inv = 1.0f / l_r;
  float ir[4];
  #pragma unroll
  for (int r = 0; r < 4; ++r) ir[r] = __shfl(inv, lg * 4 + r, 64);
  const int hgE = (lr >> 3) & 1, eE = lr & 7;
  #pragma unroll
  for (int nt = 0; nt < 8; ++nt) {
    const int ktE = h * 2 + (nt >> 2);   // col tile (K=QS=2048, KT=32)
    const int sE = nt & 3;
    #pragma unroll
    for (int r = 0; r < 4; ++r) {
      int rowi = b * SS + qbase + lg * 4 + r;
      int P = rowi >> 7, rr = rowi & 127;
      int rg = rr >> 5, l31r = rr & 31;
      int cE = ((rg * 4 + sE) * 32 + l31r) * 2 + hgE;
      size_t addr = (((size_t)(P * 32 + ktE)) << 13) + (size_t)cE * 8 + eE;
      out[addr] = (bf16)(acc[nt][r] * ir[r]);
    }
  }
}

// ---------------- launcher ----------------
// NOTE: wo_bf aliases k_buf (region C) -> the wo convert MUST run after attention.
extern "C" void kernel_launch(void* const* d_in, const int* in_sizes, int n_in,
                              void* d_out, int out_size, void* d_ws, size_t ws_size,
                              hipStream_t stream) {
  const int*   pos  = (const int*)d_in[0];
  const float* hid  = (const float*)d_in[1];
  const float* wqkv = (const float*)d_in[2];
  const float* wo   = (const float*)d_in[3];
  const float* qw   = (const float*)d_in[4];
  const float* kw   = (const float*)d_in[5];
  char* ws = (char*)d_ws;
  bf16* hid_bf  = (bf16*)(ws + 0);          // 16MB blocked, reused as attn_out (blocked)
  bf16* attn_o  = hid_bf;
  bf16* wqkv_bf = (bf16*)(ws + 16777216);   // 16MB blocked, reused as q_buf
  bf16* q_buf   = wqkv_bf;
  bf16* k_buf   = (bf16*)(ws + 33554432);   // 8MB, reused as wo_bf (blocked) AFTER attn
  bf16* wo_bf   = k_buf;
  bf16* qkv     = (bf16*)(ws + 41943040);   // 32MB (row-major)
  bf16* vT      = (bf16*)(ws + 75497472);   // 8MB
  float* tbl    = (float*)(ws + 83886080);  // 1MB

  k_cvtb2<<<dim3(2048), dim3(256), 0, stream>>>(
      hid, hid_bf, ROWS * HIDDEN / 8,
      wqkv, wqkv_bf, OC * HIDDEN / 8);
  k_table<<<dim3(512), dim3(256), 0, stream>>>(tbl);
  k_gemm<bf16><<<dim3(OC / 128, ROWS / 128), dim3(256), 0, stream>>>(
      hid_bf, wqkv_bf, qkv, ROWS, OC, HIDDEN);
  k_ropenorm<<<dim3(ROWS * 24 / 4), dim3(256), 0, stream>>>(
      qkv, q_buf, k_buf, tbl, pos, qw, kw);
  k_vt<<<dim3(SS / 64, NKV, BB), dim3(256), 0, stream>>>(qkv, vT);
  k_attn9<<<dim3(SS / 64, NHEADS, BB), dim3(256), 0, stream>>>(
      q_buf, k_buf, vT, attn_o);
  k_cvtb<<<dim3(2048), dim3(256), 0, stream>>>(wo, wo_bf, HIDDEN * QS / 8);
  k_gemm<float><<<dim3(HIDDEN / 128, ROWS / 128), dim3(256), 0, stream>>>(
      attn_o, wo_bf, (float*)d_out, ROWS, HIDDEN, QS);
}

// Round 25
// 254.287 us; speedup vs baseline: 1.0728x; 1.0465x over previous
//
#include <hip/hip_runtime.h>
#include <hip/hip_bf16.h>
#include <cstdint>
#include <cstddef>

#define HIDDEN 2048
#define NHEADS 16
#define NKV    8
#define HD     128
#define QS     (NHEADS*HD)      // 2048
#define KVS    (NKV*HD)         // 1024
#define OC     (QS + 2*KVS)     // 4096
#define BB     2
#define SS     2048
#define ROWS   (BB*SS)          // 4096

typedef __bf16 bf16;
typedef __bf16 bf16x8 __attribute__((ext_vector_type(8)));
typedef __bf16 bf16x4 __attribute__((ext_vector_type(4)));
typedef float  f32x4  __attribute__((ext_vector_type(4)));
typedef float  f32x2  __attribute__((ext_vector_type(2)));
typedef float  f32x16 __attribute__((ext_vector_type(16)));
typedef int    i32x4  __attribute__((ext_vector_type(4)));

// raw v_exp_f32 (2^x)
__device__ __forceinline__ float fexp2(float x) {
#if __has_builtin(__builtin_amdgcn_exp2f)
  return __builtin_amdgcn_exp2f(x);
#else
  return __expf(x * 0.6931471805599453f);
#endif
}

// ---- Blocked layouts ----
// GEMM1 operands (256-row x 32-k tiles, fragment order, K=2048 -> KT=64):
//   P=row>>8, kt=k>>5; rg=(row&255)>>5, l31=row&31, s=(k&31)>>4, hg=(k>>3)&1, e=k&7
//   c=((rg*2+s)*32+l31)*2+hg ; addr=((P*64+kt)<<13)+c*8+e
// GEMM2 operands keep the old 128x64 tiling (P=row>>7, kt=k>>6, rg=(row&127)>>5,
//   s=(k&63)>>4): c=((rg*4+s)*32+l31)*2+hg ; addr=((P*32+kt)<<13)+c*8+e

// ---------------- f32 -> blocked bf16 (128x64 tiling, for wo / GEMM2-B) ----------------
__global__ __launch_bounds__(256) void k_cvtb(const float* __restrict__ src,
                                              bf16* __restrict__ dst, int nchunks) {
  int G = blockIdx.x * blockDim.x + threadIdx.x;
  int stride = gridDim.x * blockDim.x;
  for (; G < nchunks; G += stride) {
    int c = G & 1023, tile = G >> 10;
    int P = tile >> 5, kt = tile & 31;
    int hg = c & 1, l31 = (c >> 1) & 31, s = (c >> 6) & 3, rg = c >> 8;
    int row = P * 128 + rg * 32 + l31;
    int k = kt * 64 + s * 16 + hg * 8;
    const f32x4* sp = (const f32x4*)(src + (size_t)row * 2048 + k);
    f32x4 a = sp[0], b2 = sp[1];
    bf16x8 o;
    o[0]=(bf16)a[0]; o[1]=(bf16)a[1]; o[2]=(bf16)a[2]; o[3]=(bf16)a[3];
    o[4]=(bf16)b2[0]; o[5]=(bf16)b2[1]; o[6]=(bf16)b2[2]; o[7]=(bf16)b2[3];
    *(bf16x8*)(dst + (size_t)G * 8) = o;
  }
}

// ---------------- merged f32 -> blocked bf16 (256x32 tiling, GEMM1 A and B) ----------------
__global__ __launch_bounds__(256) void k_cvtb2(const float* __restrict__ s0, bf16* __restrict__ d0, int n0,
                                               const float* __restrict__ s1, bf16* __restrict__ d1, int n1) {
  int G = blockIdx.x * blockDim.x + threadIdx.x;
  int stride = gridDim.x * blockDim.x;
  int total = n0 + n1;
  for (; G < total; G += stride) {
    const float* src; bf16* dst; int g;
    if (G < n0) { src = s0; dst = d0; g = G; }
    else        { src = s1; dst = d1; g = G - n0; }
    int c = g & 1023, tile = g >> 10;
    int P = tile >> 6, kt = tile & 63;
    int hg = c & 1, l31 = (c >> 1) & 31, s = (c >> 6) & 1, rg = c >> 7;  // rg 0..7
    int row = P * 256 + rg * 32 + l31;
    int k = kt * 32 + s * 16 + hg * 8;
    const f32x4* sp = (const f32x4*)(src + (size_t)row * 2048 + k);
    f32x4 a = sp[0], b2 = sp[1];
    bf16x8 o;
    o[0]=(bf16)a[0]; o[1]=(bf16)a[1]; o[2]=(bf16)a[2]; o[3]=(bf16)a[3];
    o[4]=(bf16)b2[0]; o[5]=(bf16)b2[1]; o[6]=(bf16)b2[2]; o[7]=(bf16)b2[3];
    *(bf16x8*)(dst + (size_t)g * 8) = o;
  }
}

// ---------------- RoPE cos/sin table ----------------
__global__ __launch_bounds__(256) void k_table(float* __restrict__ tbl) {
  int t = blockIdx.x * blockDim.x + threadIdx.x;   // t < SS*64
  int pos = t >> 6, i = t & 63;
  float freq = powf(10000.0f, -(float)i / 64.0f);
  float ang = (float)pos * freq;
  float sv, cv;
  sincosf(ang, &sv, &cv);
  f32x2 v; v[0] = cv; v[1] = sv;
  ((f32x2*)tbl)[t] = v;
}

// ---------------- async global->LDS helper ----------------
__device__ __forceinline__ void gll16(const void* g, void* l) {
  __builtin_amdgcn_global_load_lds((const __attribute__((address_space(1))) void*)g,
                                   (__attribute__((address_space(3))) void*)l, 16, 0, 0);
}

// ---------------- GEMM1: 256x256 tile, 8 waves, BK=32, 4-buffer counted-vmcnt pipeline ----------------
// Never drains vmcnt to 0 in the loop (T3/T4 mechanism). One barrier per K-tile.
// Race-free: buf[(t+3)&3] was last read in iteration t-1 (sealed by this
// iteration's barrier); vmcnt(8) waits exactly the oldest 4 loads = tile t (m135).
__global__ __launch_bounds__(512) void k_gemm1(const bf16* __restrict__ A,
                                               const bf16* __restrict__ Bw,
                                               bf16* __restrict__ C,
                                               int M, int N, int K) {
  const int tid = threadIdx.x;
  const int lane = tid & 63;
  const int w = tid >> 6;          // 0..7
  const int lin = blockIdx.x + gridDim.x * blockIdx.y;
  const int cpx = (gridDim.x * gridDim.y) >> 3;
  const int swz = (lin & 7) * cpx + (lin >> 3);
  const int bx = swz % gridDim.x, by = swz / gridDim.x;
  const int m0 = by * 256, n0 = bx * 256;
  __shared__ bf16 Abuf[4][8192];   // 4 x 16KB (256 rows x 32 k, fragment order)
  __shared__ bf16 Bbuf[4][8192];
  f32x16 acc[4][2] = {};
  const int l31 = lane & 31, hg = lane >> 5;
  const int rgwA = (w >> 2) * 4;   // wave's first A row-group (rows (w>>2)*128)
  const int rgwB = (w & 3) * 2;    // wave's first B row-group (cols (w&3)*64)
  const int KT = K >> 5;           // 64
  const size_t baseA = ((size_t)(m0 >> 8) * KT) << 13;
  const size_t baseB = ((size_t)(n0 >> 8) * KT) << 13;
  // prologue: stage tiles 0,1,2 (12 gll/thread outstanding)
  #pragma unroll
  for (int p = 0; p < 3; ++p) {
    #pragma unroll
    for (int i = 0; i < 2; ++i) {
      int c = tid + i * 512;
      gll16(A + baseA + ((size_t)p << 13) + (size_t)c * 8, Abuf[p] + (size_t)(c & ~63) * 8);
      gll16(Bw + baseB + ((size_t)p << 13) + (size_t)c * 8, Bbuf[p] + (size_t)(c & ~63) * 8);
    }
  }
  for (int t = 0; t < KT; ++t) {
    const int rem = KT - 1 - t;
    if (rem >= 2)      asm volatile("s_waitcnt vmcnt(8)" ::: "memory");
    else if (rem == 1) asm volatile("s_waitcnt vmcnt(4)" ::: "memory");
    else               asm volatile("s_waitcnt vmcnt(0)" ::: "memory");
    __syncthreads();                 // buf[t&3] ready; buf[(t+3)&3] reads all done
    if (t + 3 < KT) {
      const int nt3 = t + 3, nb = nt3 & 3;
      #pragma unroll
      for (int i = 0; i < 2; ++i) {
        int c = tid + i * 512;
        gll16(A + baseA + ((size_t)nt3 << 13) + (size_t)c * 8, Abuf[nb] + (size_t)(c & ~63) * 8);
        gll16(Bw + baseB + ((size_t)nt3 << 13) + (size_t)c * 8, Bbuf[nb] + (size_t)(c & ~63) * 8);
      }
    }
    const char* Ab = (const char*)Abuf[t & 3];
    const char* Bb = (const char*)Bbuf[t & 3];
    __builtin_amdgcn_s_setprio(1);
    #pragma unroll
    for (int s = 0; s < 2; ++s) {
      bf16x8 af[4], bfv[2];
      #pragma unroll
      for (int i = 0; i < 4; ++i)
        af[i] = *(const bf16x8*)(Ab + (((rgwA + i) * 2 + s) * 1024 + l31 * 32 + hg * 16));
      #pragma unroll
      for (int j = 0; j < 2; ++j)
        bfv[j] = *(const bf16x8*)(Bb + (((rgwB + j) * 2 + s) * 1024 + l31 * 32 + hg * 16));
      #pragma unroll
      for (int i = 0; i < 4; ++i)
        #pragma unroll
        for (int j = 0; j < 2; ++j)
          acc[i][j] = __builtin_amdgcn_mfma_f32_32x32x16_bf16(af[i], bfv[j], acc[i][j], 0, 0, 0);
    }
    __builtin_amdgcn_s_setprio(0);
  }
  // epilogue: C row-major (verified 32x32 C/D mapping)
  #pragma unroll
  for (int i = 0; i < 4; ++i)
    #pragma unroll
    for (int j = 0; j < 2; ++j) {
      int col = n0 + (w & 3) * 64 + j * 32 + l31;
      #pragma unroll
      for (int reg = 0; reg < 16; ++reg) {
        int row = m0 + (w >> 2) * 128 + i * 32 + 4 * hg + (reg & 3) + 8 * (reg >> 2);
        C[(size_t)row * N + col] = (bf16)acc[i][j][reg];
      }
    }
}

// ---------------- GEMM2 (verified R24 kernel): 128x128, BK=64, blocked 128x64 operands ----------------
template <typename OT>
__global__ __launch_bounds__(256) void k_gemm(const bf16* __restrict__ A,
                                              const bf16* __restrict__ Bw,
                                              OT* __restrict__ C,
                                              int M, int N, int K) {
  const int tid = threadIdx.x;
  const int lane = tid & 63;
  const int w = tid >> 6;
  const int lin = blockIdx.x + gridDim.x * blockIdx.y;
  const int cpx = (gridDim.x * gridDim.y) >> 3;
  const int swz = (lin & 7) * cpx + (lin >> 3);
  const int bx = swz % gridDim.x, by = swz / gridDim.x;
  const int m0 = by * 128, n0 = bx * 128;
  __shared__ bf16 As[128 * 64];
  __shared__ bf16 Bs[128 * 64];
  f32x16 acc[2][2] = {};
  const int wm = (w >> 1) * 64, wn = (w & 1) * 64;
  const int l31 = lane & 31, hg = lane >> 5;
  const int rgA = (w >> 1) * 2;
  const int rgB = (w & 1) * 2;
  const int KT = K >> 6;
  const int kt0 = ((lin >> 8) & 3) * (KT >> 2);
  for (int it = 0; it < KT; ++it) {
    int kt = kt0 + it; if (kt >= KT) kt -= KT;
    __syncthreads();
    const size_t tA = ((size_t)((m0 >> 7) * KT + kt)) << 13;
    const size_t tB = ((size_t)((n0 >> 7) * KT + kt)) << 13;
    #pragma unroll
    for (int i = 0; i < 4; ++i) {
      int c = tid + i * 256;
      gll16(A + tA + (size_t)c * 8, As + (size_t)(c & ~63) * 8);
      gll16(Bw + tB + (size_t)c * 8, Bs + (size_t)(c & ~63) * 8);
    }
    asm volatile("s_waitcnt vmcnt(0)" ::: "memory");
    __syncthreads();
    bf16x8 af[2][4], bfv[2][4];
    #pragma unroll
    for (int i = 0; i < 2; ++i)
      #pragma unroll
      for (int s = 0; s < 4; ++s)
        af[i][s] = *(const bf16x8*)((char*)As + (((rgA + i) * 4 + s) * 1024 + l31 * 32 + hg * 16));
    #pragma unroll
    for (int j = 0; j < 2; ++j)
      #pragma unroll
      for (int s = 0; s < 4; ++s)
        bfv[j][s] = *(const bf16x8*)((char*)Bs + (((rgB + j) * 4 + s) * 1024 + l31 * 32 + hg * 16));
    #pragma unroll
    for (int i = 0; i < 2; ++i)
      #pragma unroll
      for (int j = 0; j < 2; ++j)
        #pragma unroll
        for (int s = 0; s < 4; ++s)
          acc[i][j] = __builtin_amdgcn_mfma_f32_32x32x16_bf16(af[i][s], bfv[j][s], acc[i][j], 0, 0, 0);
  }
  #pragma unroll
  for (int i = 0; i < 2; ++i)
    #pragma unroll
    for (int j = 0; j < 2; ++j) {
      int col = n0 + wn + j * 32 + l31;
      #pragma unroll
      for (int reg = 0; reg < 16; ++reg) {
        int row = m0 + wm + i * 32 + 4 * hg + (reg & 3) + 8 * (reg >> 2);
        C[(size_t)row * N + col] = (OT)acc[i][j][reg];
      }
    }
}

// ---------------- per-head RMSNorm + RoPE ----------------
__global__ __launch_bounds__(256) void k_ropenorm(const bf16* __restrict__ qkv,
                                                  bf16* __restrict__ qb, bf16* __restrict__ kb,
                                                  const float* __restrict__ tbl,
                                                  const int* __restrict__ pos,
                                                  const float* __restrict__ qw,
                                                  const float* __restrict__ kw) {
  int gw = blockIdx.x * 4 + (threadIdx.x >> 6);
  int lane = threadIdx.x & 63;
  int h = gw % 24;
  int rem = gw / 24;
  int s = rem & (SS - 1);
  int b = rem >> 11;
  size_t row = (size_t)b * SS + s;
  int col0 = (h < 16) ? h * HD : QS + (h - 16) * HD;
  unsigned u = *(const unsigned*)(qkv + row * OC + col0 + lane * 2);
  float x0 = __uint_as_float((u & 0xffffu) << 16);
  float x1 = __uint_as_float(u & 0xffff0000u);
  float ssq = x0 * x0 + x1 * x1;
  for (int m = 1; m < 64; m <<= 1) ssq += __shfl_xor(ssq, m, 64);
  float r = rsqrtf(ssq * (1.0f / 128.0f) + 1e-6f);
  const float* wv = (h < 16) ? qw : kw;
  float y0 = x0 * r * wv[lane * 2], y1 = x1 * r * wv[lane * 2 + 1];
  float p0 = __shfl_xor(y0, 32, 64), p1 = __shfl_xor(y1, 32, 64);
  int p = pos[row];
  f32x4 cs = *(const f32x4*)(tbl + (size_t)p * 128 + (lane & 31) * 4);
  float o0, o1;
  if (lane < 32) { o0 = y0 * cs[0] - p0 * cs[1]; o1 = y1 * cs[2] - p1 * cs[3]; }
  else           { o0 = y0 * cs[0] + p0 * cs[1]; o1 = y1 * cs[2] + p1 * cs[3]; }
  bf16* dst; size_t drow;
  if (h < 16) {
    const float scl2 = 0.12753102f;
    o0 *= scl2; o1 *= scl2;
    dst = qb; drow = ((size_t)b * NHEADS + h) * SS + s;
  } else {
    dst = kb; drow = ((size_t)b * NKV + (h - 16)) * SS + s;
  }
  bf16 v0 = (bf16)o0, v1 = (bf16)o1;
  unsigned short q0, q1;
  __builtin_memcpy(&q0, &v0, 2); __builtin_memcpy(&q1, &v1, 2);
  *(unsigned*)(dst + drow * HD + lane * 2) = (unsigned)q0 | ((unsigned)q1 << 16);
}

// ---------------- V transpose ----------------
__global__ __launch_bounds__(256) void k_vt(const bf16* __restrict__ qkv,
                                            bf16* __restrict__ vT) {
  __shared__ bf16 T[64 * 136];
  int tid = threadIdx.x;
  int st = blockIdx.x, kv = blockIdx.y, b = blockIdx.z;
  int s0 = st * 64;
  for (int i = 0; i < 4; ++i) {
    int c = tid + i * 256;
    int sl = c >> 4, dc = c & 15;
    i32x4 v = *(const i32x4*)(qkv + (size_t)(b * SS + s0 + sl) * OC + QS + KVS + kv * HD + dc * 8);
    *(i32x4*)(T + sl * 136 + dc * 8) = v;
  }
  __syncthreads();
  for (int i = 0; i < 4; ++i) {
    int c = tid + i * 256;
    int d = c >> 3, sg = c & 7;
    bf16x8 o;
    for (int j = 0; j < 8; ++j) o[j] = T[(sg * 8 + j) * 136 + d];
    *(bf16x8*)(vT + ((size_t)(b * NKV + kv) * HD + d) * SS + s0 + sg * 8) = o;
  }
}

// ---------------- flash attention (R24-verified; blocked 128x64 attn_o write) ----------------
__global__ __launch_bounds__(256) void k_attn9(const bf16* __restrict__ qb,
                                               const bf16* __restrict__ kb,
                                               const bf16* __restrict__ vT,
                                               bf16* __restrict__ out) {
  __shared__ bf16 Kl[64 * 128];
  __shared__ bf16 Vl[128 * 64];
  __shared__ bf16 Pl[4][16 * 64];
  const int tid = threadIdx.x, lane = tid & 63, w = tid >> 6;
  const int L = blockIdx.x + 32 * (blockIdx.y + 16 * blockIdx.z);
  const int r8 = L & 7;
  const int c4 = (L >> 3) & 3;
  const int i32_ = L >> 5;
  const int g = r8 * 4 + c4;
  const int h = g >> 1, b = g & 1;
  const int a_ = i32_ & 7, m_ = i32_ >> 3;
  const int qt = (m_ == 0) ? a_ : (m_ == 1) ? (15 - a_) : (m_ == 2) ? (16 + a_) : (31 - a_);
  const int kvh = h >> 1;
  const int lr = lane & 15, lg = lane >> 4;
  const int qbase = qt * 64 + w * 16;
  const float NEG = -3.0e38f;
  bf16x8 qf[4];
  {
    const bf16* qrow = qb + ((size_t)(b * NHEADS + h) * SS + qbase + lr) * HD;
    #pragma unroll
    for (int ks = 0; ks < 4; ++ks) qf[ks] = *(const bf16x8*)(qrow + ks * 32 + lg * 8);
  }
  f32x4 acc[8] = {};
  float m_r = NEG, l_r = 0.0f;
  const bf16* Kg = kb + (size_t)(b * NKV + kvh) * SS * HD;
  const bf16* Vg = vT + (size_t)(b * NKV + kvh) * HD * SS;
  for (int t = 0; t <= qt; ++t) {
    const int kv0 = t * 64;
    __syncthreads();
    #pragma unroll
    for (int i = 0; i < 4; ++i) {
      int c = tid + i * 256;
      int r_ = c >> 4;
      int ch = (c & 15) ^ (r_ & 7);
      gll16(Kg + (size_t)(kv0 + r_) * HD + ch * 8, Kl + (size_t)(c & ~63) * 8);
    }
    #pragma unroll
    for (int i = 0; i < 4; ++i) {
      int c = tid + i * 256;
      int d = c >> 3;
      int ch = (c & 7) ^ (d & 7);
      gll16(Vg + (size_t)d * SS + kv0 + ch * 8, Vl + (size_t)(c & ~63) * 8);
    }
    asm volatile("s_waitcnt vmcnt(0)" ::: "memory");
    __syncthreads();
    f32x4 sf[4];
    __builtin_amdgcn_s_setprio(1);
    #pragma unroll
    for (int mt = 0; mt < 4; ++mt) {
      f32x4 a2 = {0.f, 0.f, 0.f, 0.f};
      const int rrow = mt * 16 + lr;
      #pragma unroll
      for (int ks = 0; ks < 4; ++ks) {
        bf16x8 kf = *(const bf16x8*)((char*)Kl + ((rrow * 256 + ks * 64 + lg * 16) ^ ((rrow & 7) << 4)));
        a2 = __builtin_amdgcn_mfma_f32_16x16x32_bf16(kf, qf[ks], a2, 0, 0, 0);
      }
      sf[mt] = a2;
    }
    __builtin_amdgcn_s_setprio(0);
    const int qg = qbase + lr;
    float pm = NEG;
    if (t == qt) {
      #pragma unroll
      for (int mt = 0; mt < 4; ++mt)
        #pragma unroll
        for (int r = 0; r < 4; ++r) {
          int kvg = kv0 + mt * 16 + lg * 4 + r;
          float v = sf[mt][r];
          if (kvg > qg) v = NEG;
          sf[mt][r] = v;
          pm = fmaxf(pm, v);
        }
    } else {
      #pragma unroll
      for (int mt = 0; mt < 4; ++mt)
        #pragma unroll
        for (int r = 0; r < 4; ++r) pm = fmaxf(pm, sf[mt][r]);
    }
    pm = fmaxf(pm, __shfl_xor(pm, 16, 64));
    pm = fmaxf(pm, __shfl_xor(pm, 32, 64));
    if (!__all(pm <= m_r + 11.5415603f)) {
      const float mn = fmaxf(m_r, pm);
      const float scale = fexp2(m_r - mn);
      float sr[4];
      #pragma unroll
      for (int r = 0; r < 4; ++r) sr[r] = __shfl(scale, lg * 4 + r, 64);
      #pragma unroll
      for (int nt = 0; nt < 8; ++nt)
        #pragma unroll
        for (int r = 0; r < 4; ++r) acc[nt][r] *= sr[r];
      l_r *= scale;
      m_r = mn;
    }
    float ts = 0.f;
    #pragma unroll
    for (int mt = 0; mt < 4; ++mt)
      #pragma unroll
      for (int r = 0; r < 4; ++r) {
        float pv = fexp2(sf[mt][r] - m_r);
        sf[mt][r] = pv;
        ts += pv;
      }
    ts += __shfl_xor(ts, 16, 64);
    ts += __shfl_xor(ts, 32, 64);
    l_r += ts;
    #pragma unroll
    for (int mt = 0; mt < 4; ++mt) {
      bf16x4 pk;
      #pragma unroll
      for (int r = 0; r < 4; ++r) pk[r] = (bf16)sf[mt][r];
      *(bf16x4*)((char*)&Pl[w][0] + ((lr * 128 + mt * 32 + lg * 8) ^ ((lr & 7) << 4))) = pk;
    }
    __builtin_amdgcn_s_setprio(1);
    #pragma unroll
    for (int kk = 0; kk < 2; ++kk) {
      bf16x8 pa = *(const bf16x8*)((char*)&Pl[w][0] + ((lr * 128 + kk * 64 + lg * 16) ^ ((lr & 7) << 4)));
      #pragma unroll
      for (int nt = 0; nt < 8; ++nt) {
        const int d = nt * 16 + lr;
        bf16x8 vbf = *(const bf16x8*)((char*)Vl + ((d * 128 + kk * 64 + lg * 16) ^ ((d & 7) << 4)));
        acc[nt] = __builtin_amdgcn_mfma_f32_16x16x32_bf16(pa, vbf, acc[nt], 0, 0, 0);
      }
    }
    __builtin_amdgcn_s_setprio(0);
  }
  const float inv = 1.0f / l_r;
  float ir[4];
  #pragma unroll
  for (int r = 0; r < 4; ++r) ir[r] = __shfl(inv, lg * 4 + r, 64);
  const int hgE = (lr >> 3) & 1, eE = lr & 7;
  #pragma unroll
  for (int nt = 0; nt < 8; ++nt) {
    const int ktE = h * 2 + (nt >> 2);
    const int sE = nt & 3;
    #pragma unroll
    for (int r = 0; r < 4; ++r) {
      int rowi = b * SS + qbase + lg * 4 + r;
      int P = rowi >> 7, rr = rowi & 127;
      int rg = rr >> 5, l31r = rr & 31;
      int cE = ((rg * 4 + sE) * 32 + l31r) * 2 + hgE;
      size_t addr = (((size_t)(P * 32 + ktE)) << 13) + (size_t)cE * 8 + eE;
      out[addr] = (bf16)(acc[nt][r] * ir[r]);
    }
  }
}

// ---------------- launcher ----------------
extern "C" void kernel_launch(void* const* d_in, const int* in_sizes, int n_in,
                              void* d_out, int out_size, void* d_ws, size_t ws_size,
                              hipStream_t stream) {
  const int*   pos  = (const int*)d_in[0];
  const float* hid  = (const float*)d_in[1];
  const float* wqkv = (const float*)d_in[2];
  const float* wo   = (const float*)d_in[3];
  const float* qw   = (const float*)d_in[4];
  const float* kw   = (const float*)d_in[5];
  char* ws = (char*)d_ws;
  bf16* hid_bf  = (bf16*)(ws + 0);          // 16MB blocked(256x32), reused as attn_out (blocked 128x64)
  bf16* attn_o  = hid_bf;
  bf16* wqkv_bf = (bf16*)(ws + 16777216);   // 16MB blocked(256x32), reused as q_buf
  bf16* q_buf   = wqkv_bf;
  bf16* k_buf   = (bf16*)(ws + 33554432);   // 8MB, reused as wo_bf (blocked 128x64) AFTER attn
  bf16* wo_bf   = k_buf;
  bf16* qkv     = (bf16*)(ws + 41943040);   // 32MB (row-major)
  bf16* vT      = (bf16*)(ws + 75497472);   // 8MB
  float* tbl    = (float*)(ws + 83886080);  // 1MB

  k_cvtb2<<<dim3(2048), dim3(256), 0, stream>>>(
      hid, hid_bf, ROWS * HIDDEN / 8,
      wqkv, wqkv_bf, OC * HIDDEN / 8);
  k_table<<<dim3(512), dim3(256), 0, stream>>>(tbl);
  k_gemm1<<<dim3(OC / 256, ROWS / 256), dim3(512), 0, stream>>>(
      hid_bf, wqkv_bf, qkv, ROWS, OC, HIDDEN);
  k_ropenorm<<<dim3(ROWS * 24 / 4), dim3(256), 0, stream>>>(
      qkv, q_buf, k_buf, tbl, pos, qw, kw);
  k_vt<<<dim3(SS / 64, NKV, BB), dim3(256), 0, stream>>>(qkv, vT);
  k_attn9<<<dim3(SS / 64, NHEADS, BB), dim3(256), 0, stream>>>(
      q_buf, k_buf, vT, attn_o);
  k_cvtb<<<dim3(2048), dim3(256), 0, stream>>>(wo, wo_bf, HIDDEN * QS / 8);
  k_gemm<float><<<dim3(HIDDEN / 128, ROWS / 128), dim3(256), 0, stream>>>(
      attn_o, wo_bf, (float*)d_out, ROWS, HIDDEN, QS);
}